// Round 2
// baseline (479.230 us; speedup 1.0000x reference)
//
#include <hip/hip_runtime.h>

#define N_NODES 50000
#define E_EDGES 250000
#define IN_F 9
#define OUT_F 84
#define GROUPS 21            // OUT_F / 4
#define BN_EPS 1e-5f

// ---------------------------------------------------------------------------
// K0: zero the stats accumulator in d_ws (poisoned 0xAA before every launch)
// ---------------------------------------------------------------------------
__global__ void zero_stats_kernel(float* __restrict__ stats) {
    int i = threadIdx.x;
    if (i < 2 * OUT_F) stats[i] = 0.0f;
}

// ---------------------------------------------------------------------------
// K1: out[n, :] = x[n, :] @ root + bias      (base for scatter accumulation)
// one thread per (node, 4-channel group)
// ---------------------------------------------------------------------------
__global__ void init_kernel(const float* __restrict__ x,
                            const float* __restrict__ root,
                            const float* __restrict__ bias,
                            float* __restrict__ out) {
    __shared__ __align__(16) float rs[IN_F * OUT_F];
    __shared__ __align__(16) float bs[OUT_F];
    for (int i = threadIdx.x; i < IN_F * OUT_F; i += blockDim.x) rs[i] = root[i];
    if (threadIdx.x < OUT_F) bs[threadIdx.x] = bias[threadIdx.x];
    __syncthreads();

    int gid = blockIdx.x * blockDim.x + threadIdx.x;
    if (gid >= N_NODES * GROUPS) return;
    int n = gid / GROUPS;
    int g = gid - n * GROUPS;

    float xv[IN_F];
#pragma unroll
    for (int i = 0; i < IN_F; ++i) xv[i] = x[n * IN_F + i];

    float4 acc = *(const float4*)&bs[g * 4];
#pragma unroll
    for (int i = 0; i < IN_F; ++i) {
        float4 w = *(const float4*)&rs[i * OUT_F + g * 4];
        acc.x += xv[i] * w.x;
        acc.y += xv[i] * w.y;
        acc.z += xv[i] * w.z;
        acc.w += xv[i] * w.w;
    }
    // out row offset: n*84 + g*4 == gid*4  (16B aligned)
    *(float4*)&out[gid * 4] = acc;
}

// ---------------------------------------------------------------------------
// K2: per-edge message + scatter-add.
// Since EDIM==1:  msg[e,o] = ea[e] * dot(x[src], W[:,o]) + dot(x[src], B[:,o])
// one thread per (edge, 4-channel group); 4 scalar atomicAdds to out[dst].
// edge_index arrives as int32 (harness converts int64 -> int).
// ---------------------------------------------------------------------------
__global__ void edge_kernel(const float* __restrict__ x,
                            const int* __restrict__ ei,
                            const float* __restrict__ ea,
                            const float* __restrict__ nw,
                            const float* __restrict__ nb,
                            float* __restrict__ out) {
    __shared__ __align__(16) float Ws[IN_F * OUT_F];
    __shared__ __align__(16) float Bs[IN_F * OUT_F];
    for (int i = threadIdx.x; i < IN_F * OUT_F; i += blockDim.x) {
        Ws[i] = nw[i];
        Bs[i] = nb[i];
    }
    __syncthreads();

    int gid = blockIdx.x * blockDim.x + threadIdx.x;
    if (gid >= E_EDGES * GROUPS) return;
    int e = gid / GROUPS;
    int g = gid - e * GROUPS;

    int src = ei[e];
    int dst = ei[E_EDGES + e];
    float a = ea[e];

    float xv[IN_F];
#pragma unroll
    for (int i = 0; i < IN_F; ++i) xv[i] = x[src * IN_F + i];

    float4 accA = make_float4(0.f, 0.f, 0.f, 0.f);
    float4 accB = make_float4(0.f, 0.f, 0.f, 0.f);
#pragma unroll
    for (int i = 0; i < IN_F; ++i) {
        float4 w = *(const float4*)&Ws[i * OUT_F + g * 4];
        float4 b = *(const float4*)&Bs[i * OUT_F + g * 4];
        accA.x += xv[i] * w.x;  accB.x += xv[i] * b.x;
        accA.y += xv[i] * w.y;  accB.y += xv[i] * b.y;
        accA.z += xv[i] * w.z;  accB.z += xv[i] * b.z;
        accA.w += xv[i] * w.w;  accB.w += xv[i] * b.w;
    }

    float4 m;
    m.x = a * accA.x + accB.x;
    m.y = a * accA.y + accB.y;
    m.z = a * accA.z + accB.z;
    m.w = a * accA.w + accB.w;

    float* o = &out[(long)dst * OUT_F + g * 4];
    atomicAdd(o + 0, m.x);
    atomicAdd(o + 1, m.y);
    atomicAdd(o + 2, m.z);
    atomicAdd(o + 3, m.w);
}

// ---------------------------------------------------------------------------
// K3: per-channel sum & sumsq over all N rows.
// grid (21 channel-groups, 32 row-splits), 256 threads; shuffle-reduce per
// wave; atomic into stats[0..83]=sum, stats[84..167]=sumsq.
// ---------------------------------------------------------------------------
__global__ void stats_kernel(const float* __restrict__ out,
                             float* __restrict__ stats) {
    int g = blockIdx.x;
    float4 s = make_float4(0.f, 0.f, 0.f, 0.f);
    float4 q = make_float4(0.f, 0.f, 0.f, 0.f);
    for (int r = blockIdx.y * blockDim.x + threadIdx.x; r < N_NODES;
         r += gridDim.y * blockDim.x) {
        float4 v = *(const float4*)&out[(long)r * OUT_F + g * 4];
        s.x += v.x; s.y += v.y; s.z += v.z; s.w += v.w;
        q.x += v.x * v.x; q.y += v.y * v.y; q.z += v.z * v.z; q.w += v.w * v.w;
    }
#pragma unroll
    for (int off = 32; off > 0; off >>= 1) {
        s.x += __shfl_down(s.x, off); s.y += __shfl_down(s.y, off);
        s.z += __shfl_down(s.z, off); s.w += __shfl_down(s.w, off);
        q.x += __shfl_down(q.x, off); q.y += __shfl_down(q.y, off);
        q.z += __shfl_down(q.z, off); q.w += __shfl_down(q.w, off);
    }
    if ((threadIdx.x & 63) == 0) {
        atomicAdd(&stats[g * 4 + 0], s.x);
        atomicAdd(&stats[g * 4 + 1], s.y);
        atomicAdd(&stats[g * 4 + 2], s.z);
        atomicAdd(&stats[g * 4 + 3], s.w);
        atomicAdd(&stats[OUT_F + g * 4 + 0], q.x);
        atomicAdd(&stats[OUT_F + g * 4 + 1], q.y);
        atomicAdd(&stats[OUT_F + g * 4 + 2], q.z);
        atomicAdd(&stats[OUT_F + g * 4 + 3], q.w);
    }
}

// ---------------------------------------------------------------------------
// K4: BatchNorm normalize in place.
// ---------------------------------------------------------------------------
__global__ void norm_kernel(float* __restrict__ out,
                            const float* __restrict__ stats,
                            const float* __restrict__ gamma,
                            const float* __restrict__ beta) {
    int gid = blockIdx.x * blockDim.x + threadIdx.x;
    if (gid >= N_NODES * GROUPS) return;
    int g = gid % GROUPS;

    const float inv_n = 1.0f / (float)N_NODES;
    float4 s = *(const float4*)&stats[g * 4];
    float4 q = *(const float4*)&stats[OUT_F + g * 4];
    float4 gm = *(const float4*)&gamma[g * 4];
    float4 bt = *(const float4*)&beta[g * 4];

    float4 v = *(float4*)&out[gid * 4];

    float mx = s.x * inv_n, my = s.y * inv_n, mz = s.z * inv_n, mw = s.w * inv_n;
    float ix = rsqrtf(q.x * inv_n - mx * mx + BN_EPS) * gm.x;
    float iy = rsqrtf(q.y * inv_n - my * my + BN_EPS) * gm.y;
    float iz = rsqrtf(q.z * inv_n - mz * mz + BN_EPS) * gm.z;
    float iw = rsqrtf(q.w * inv_n - mw * mw + BN_EPS) * gm.w;

    v.x = (v.x - mx) * ix + bt.x;
    v.y = (v.y - my) * iy + bt.y;
    v.z = (v.z - mz) * iz + bt.z;
    v.w = (v.w - mw) * iw + bt.w;

    *(float4*)&out[gid * 4] = v;
}

extern "C" void kernel_launch(void* const* d_in, const int* in_sizes, int n_in,
                              void* d_out, int out_size, void* d_ws, size_t ws_size,
                              hipStream_t stream) {
    const float* x     = (const float*)d_in[0];
    const int*   ei    = (const int*)d_in[1];     // int64 in ref -> int32 here
    const float* ea    = (const float*)d_in[2];
    const float* nw    = (const float*)d_in[3];
    const float* nb    = (const float*)d_in[4];
    const float* root  = (const float*)d_in[5];
    const float* bias  = (const float*)d_in[6];
    const float* gamma = (const float*)d_in[7];
    const float* beta  = (const float*)d_in[8];
    float*       out   = (float*)d_out;
    float*       stats = (float*)d_ws;            // 168 floats

    const int nthreads_node = N_NODES * GROUPS;   // 1,050,000
    const int nthreads_edge = E_EDGES * GROUPS;   // 5,250,000

    zero_stats_kernel<<<1, 256, 0, stream>>>(stats);
    init_kernel<<<(nthreads_node + 255) / 256, 256, 0, stream>>>(x, root, bias, out);
    edge_kernel<<<(nthreads_edge + 255) / 256, 256, 0, stream>>>(x, ei, ea, nw, nb, out);
    stats_kernel<<<dim3(GROUPS, 32), 256, 0, stream>>>(out, stats);
    norm_kernel<<<(nthreads_node + 255) / 256, 256, 0, stream>>>(out, stats, gamma, beta);
}

// Round 3
// 195.779 us; speedup vs baseline: 2.4478x; 2.4478x over previous
//
#include <hip/hip_runtime.h>

#define N_NODES 50000
#define E_EDGES 250000
#define IN_F 9
#define OUT_F 84
#define GROUPS 21            // OUT_F / 4
#define BN_EPS 1e-5f

// workspace layout (floats):
//   [0, 168)                  : BN stats (sum[84], sumsq[84])
//   [256, 256 + N*18)         : S buffer — per node: S0[9] then S1[9]
#define STATS_OFF 0
#define S_OFF 256
#define S_FLOATS (N_NODES * 18)
#define ZERO_FLOATS (S_OFF + S_FLOATS)   // 900256, multiple of 4

// ---------------------------------------------------------------------------
// K0: zero stats + S buffer (ws is poisoned 0xAA before every launch)
// ---------------------------------------------------------------------------
__global__ void zero_ws_kernel(float4* __restrict__ ws4) {
    int i = blockIdx.x * blockDim.x + threadIdx.x;
    if (i < ZERO_FLOATS / 4)
        ws4[i] = make_float4(0.f, 0.f, 0.f, 0.f);
}

// ---------------------------------------------------------------------------
// K1: edge scatter, algebraically collapsed.
//   S0[dst] += x[src]          (9 floats)
//   S1[dst] += ea[e] * x[src]  (9 floats)
// thread per (edge, i in 0..8) -> 2.25M threads, 2 atomics each (4.5M total,
// vs 21M in the previous formulation; accumulator 3.6 MB vs 16.8 MB).
// ---------------------------------------------------------------------------
__global__ void scatter_kernel(const float* __restrict__ x,
                               const int* __restrict__ ei,
                               const float* __restrict__ ea,
                               float* __restrict__ S) {
    int gid = blockIdx.x * blockDim.x + threadIdx.x;
    if (gid >= E_EDGES * IN_F) return;
    int e = gid / IN_F;
    int i = gid - e * IN_F;

    int src = ei[e];
    int dst = ei[E_EDGES + e];
    float a = ea[e];
    float xv = x[src * IN_F + i];

    atomicAdd(&S[dst * 18 + i], xv);
    atomicAdd(&S[dst * 18 + 9 + i], a * xv);
}

// ---------------------------------------------------------------------------
// K2: fused node kernel.
//   out[n,:] = x[n]@root + S1[n]@W + S0[n]@B + bias
// thread per (node, 4-channel group). W/B/root/bias staged in LDS as float4.
// ---------------------------------------------------------------------------
__global__ void node_kernel(const float* __restrict__ x,
                            const float* __restrict__ S,
                            const float* __restrict__ nw,
                            const float* __restrict__ nb,
                            const float* __restrict__ root,
                            const float* __restrict__ bias,
                            float* __restrict__ out) {
    __shared__ __align__(16) float4 Ws[IN_F * GROUPS];
    __shared__ __align__(16) float4 Bs[IN_F * GROUPS];
    __shared__ __align__(16) float4 Rs[IN_F * GROUPS];
    __shared__ __align__(16) float4 bs[GROUPS];
    for (int t = threadIdx.x; t < IN_F * GROUPS; t += blockDim.x) {
        Ws[t] = ((const float4*)nw)[t];
        Bs[t] = ((const float4*)nb)[t];
        Rs[t] = ((const float4*)root)[t];
    }
    if (threadIdx.x < GROUPS) bs[threadIdx.x] = ((const float4*)bias)[threadIdx.x];
    __syncthreads();

    int gid = blockIdx.x * blockDim.x + threadIdx.x;
    if (gid >= N_NODES * GROUPS) return;
    int n = gid / GROUPS;
    int g = gid - n * GROUPS;

    float xv[IN_F], s0[IN_F], s1[IN_F];
#pragma unroll
    for (int i = 0; i < IN_F; ++i) {
        xv[i] = x[n * IN_F + i];
        s0[i] = S[n * 18 + i];
        s1[i] = S[n * 18 + 9 + i];
    }

    float4 acc = bs[g];
#pragma unroll
    for (int i = 0; i < IN_F; ++i) {
        float4 r = Rs[i * GROUPS + g];
        float4 w = Ws[i * GROUPS + g];
        float4 b = Bs[i * GROUPS + g];
        acc.x += xv[i] * r.x + s1[i] * w.x + s0[i] * b.x;
        acc.y += xv[i] * r.y + s1[i] * w.y + s0[i] * b.y;
        acc.z += xv[i] * r.z + s1[i] * w.z + s0[i] * b.z;
        acc.w += xv[i] * r.w + s1[i] * w.w + s0[i] * b.w;
    }
    *(float4*)&out[gid * 4] = acc;   // gid*4 == n*84 + g*4, 16B aligned
}

// ---------------------------------------------------------------------------
// K3: per-channel sum & sumsq -> stats[0..83]=sum, stats[84..167]=sumsq
// ---------------------------------------------------------------------------
__global__ void stats_kernel(const float* __restrict__ out,
                             float* __restrict__ stats) {
    int g = blockIdx.x;
    float4 s = make_float4(0.f, 0.f, 0.f, 0.f);
    float4 q = make_float4(0.f, 0.f, 0.f, 0.f);
    for (int r = blockIdx.y * blockDim.x + threadIdx.x; r < N_NODES;
         r += gridDim.y * blockDim.x) {
        float4 v = *(const float4*)&out[(long)r * OUT_F + g * 4];
        s.x += v.x; s.y += v.y; s.z += v.z; s.w += v.w;
        q.x += v.x * v.x; q.y += v.y * v.y; q.z += v.z * v.z; q.w += v.w * v.w;
    }
#pragma unroll
    for (int off = 32; off > 0; off >>= 1) {
        s.x += __shfl_down(s.x, off); s.y += __shfl_down(s.y, off);
        s.z += __shfl_down(s.z, off); s.w += __shfl_down(s.w, off);
        q.x += __shfl_down(q.x, off); q.y += __shfl_down(q.y, off);
        q.z += __shfl_down(q.z, off); q.w += __shfl_down(q.w, off);
    }
    if ((threadIdx.x & 63) == 0) {
        atomicAdd(&stats[g * 4 + 0], s.x);
        atomicAdd(&stats[g * 4 + 1], s.y);
        atomicAdd(&stats[g * 4 + 2], s.z);
        atomicAdd(&stats[g * 4 + 3], s.w);
        atomicAdd(&stats[OUT_F + g * 4 + 0], q.x);
        atomicAdd(&stats[OUT_F + g * 4 + 1], q.y);
        atomicAdd(&stats[OUT_F + g * 4 + 2], q.z);
        atomicAdd(&stats[OUT_F + g * 4 + 3], q.w);
    }
}

// ---------------------------------------------------------------------------
// K4: BatchNorm normalize in place.
// ---------------------------------------------------------------------------
__global__ void norm_kernel(float* __restrict__ out,
                            const float* __restrict__ stats,
                            const float* __restrict__ gamma,
                            const float* __restrict__ beta) {
    int gid = blockIdx.x * blockDim.x + threadIdx.x;
    if (gid >= N_NODES * GROUPS) return;
    int g = gid % GROUPS;

    const float inv_n = 1.0f / (float)N_NODES;
    float4 s = *(const float4*)&stats[g * 4];
    float4 q = *(const float4*)&stats[OUT_F + g * 4];
    float4 gm = *(const float4*)&gamma[g * 4];
    float4 bt = *(const float4*)&beta[g * 4];

    float4 v = *(float4*)&out[gid * 4];

    float mx = s.x * inv_n, my = s.y * inv_n, mz = s.z * inv_n, mw = s.w * inv_n;
    float ix = rsqrtf(q.x * inv_n - mx * mx + BN_EPS) * gm.x;
    float iy = rsqrtf(q.y * inv_n - my * my + BN_EPS) * gm.y;
    float iz = rsqrtf(q.z * inv_n - mz * mz + BN_EPS) * gm.z;
    float iw = rsqrtf(q.w * inv_n - mw * mw + BN_EPS) * gm.w;

    v.x = (v.x - mx) * ix + bt.x;
    v.y = (v.y - my) * iy + bt.y;
    v.z = (v.z - mz) * iz + bt.z;
    v.w = (v.w - mw) * iw + bt.w;

    *(float4*)&out[gid * 4] = v;
}

extern "C" void kernel_launch(void* const* d_in, const int* in_sizes, int n_in,
                              void* d_out, int out_size, void* d_ws, size_t ws_size,
                              hipStream_t stream) {
    const float* x     = (const float*)d_in[0];
    const int*   ei    = (const int*)d_in[1];     // int64 in ref -> int32 here
    const float* ea    = (const float*)d_in[2];
    const float* nw    = (const float*)d_in[3];
    const float* nb    = (const float*)d_in[4];
    const float* root  = (const float*)d_in[5];
    const float* bias  = (const float*)d_in[6];
    const float* gamma = (const float*)d_in[7];
    const float* beta  = (const float*)d_in[8];
    float*       out   = (float*)d_out;

    float* ws    = (float*)d_ws;
    float* stats = ws + STATS_OFF;   // 168 floats
    float* S     = ws + S_OFF;       // N*18 floats (3.6 MB)

    const int nthreads_node    = N_NODES * GROUPS;   // 1,050,000
    const int nthreads_scatter = E_EDGES * IN_F;     // 2,250,000

    zero_ws_kernel<<<(ZERO_FLOATS / 4 + 255) / 256, 256, 0, stream>>>((float4*)ws);
    scatter_kernel<<<(nthreads_scatter + 255) / 256, 256, 0, stream>>>(x, ei, ea, S);
    node_kernel<<<(nthreads_node + 255) / 256, 256, 0, stream>>>(x, S, nw, nb, root, bias, out);
    stats_kernel<<<dim3(GROUPS, 32), 256, 0, stream>>>(out, stats);
    norm_kernel<<<(nthreads_node + 255) / 256, 256, 0, stream>>>(out, stats, gamma, beta);
}